// Round 2
// baseline (1496.515 us; speedup 1.0000x reference)
//
#include <hip/hip_runtime.h>
#include <math.h>

#define DIM   256
#define NP    512
#define RB    16
#define NT    256
#define KSEL  5

__global__ __launch_bounds__(NT, 2) void hub_kernel(
    const float* __restrict__ x,
    const float* __restrict__ protos,
    float* __restrict__ out)
{
    __shared__ float xs[RB][DIM];        // 16 KB (raw x, then normalized xn)
    __shared__ float sims[RB][NP];       // 32 KB
    __shared__ float nrm[RB];
    __shared__ float top5v[RB][KSEL];
    __shared__ int   top5i[RB][KSEL];

    const int tid  = threadIdx.x;
    const int wave = tid >> 6;
    const int lane = tid & 63;
    const size_t r0 = (size_t)blockIdx.x * RB;

    // ---- stage x tile into LDS (coalesced float4) ----
    {
        const float4* xg = (const float4*)(x + r0 * DIM);
        float4* xs4 = (float4*)&xs[0][0];
        #pragma unroll
        for (int i = 0; i < (RB*DIM/4)/NT; ++i)   // 4 iters
            xs4[tid + i*NT] = xg[tid + i*NT];
    }
    __syncthreads();

    // ---- row norms: exact f64 sum -> f32 (within 1 ulp of any f32 reduction;
    //      per-row uniform scale cannot reorder that row's sims) ----
    #pragma unroll
    for (int rr = 0; rr < RB/4; ++rr) {
        const int r = wave * (RB/4) + rr;
        double sq = 0.0;
        #pragma unroll
        for (int j = 0; j < 4; ++j) {
            double xv = (double)xs[r][lane*4 + j];
            sq += xv * xv;
        }
        #pragma unroll
        for (int s = 32; s > 0; s >>= 1) sq += __shfl_xor(sq, s);
        if (lane == 0) nrm[r] = fmaxf(sqrtf((float)sq), 1e-12f);
    }
    __syncthreads();

    // ---- normalize in place: IEEE f32 divide, matching ref's xn = fl32(x/nrm) ----
    #pragma unroll
    for (int i = 0; i < (RB*DIM)/NT; ++i) {       // 16 iters
        int idx = tid + i*NT;
        int r = idx >> 8, d = idx & (DIM-1);
        xs[r][d] = xs[r][d] / nrm[r];
    }
    __syncthreads();

    // ---- sims: strict sequential-FMA chain over d=0..255 (single f32 accum,
    //      products unrounded) — the CPU/GPU GEMM k-order signature ----
    float acc0[RB], acc1[RB];
    #pragma unroll
    for (int r = 0; r < RB; ++r) { acc0[r] = 0.f; acc1[r] = 0.f; }
    const float* p0g = protos + (size_t)tid * DIM;
    const float* p1g = protos + (size_t)(tid + 256) * DIM;
    for (int kc = 0; kc < DIM; kc += 32) {
        float4 a0[8], a1[8];
        #pragma unroll
        for (int j = 0; j < 8; ++j) {
            a0[j] = ((const float4*)(p0g + kc))[j];
            a1[j] = ((const float4*)(p1g + kc))[j];
        }
        #pragma unroll
        for (int r = 0; r < RB; ++r) {
            const float4* xr = (const float4*)(&xs[r][kc]);   // wave-uniform → LDS broadcast
            #pragma unroll
            for (int j = 0; j < 8; ++j) {
                float4 xv = xr[j];
                acc0[r] = fmaf(xv.x, a0[j].x, acc0[r]);
                acc0[r] = fmaf(xv.y, a0[j].y, acc0[r]);
                acc0[r] = fmaf(xv.z, a0[j].z, acc0[r]);
                acc0[r] = fmaf(xv.w, a0[j].w, acc0[r]);
                acc1[r] = fmaf(xv.x, a1[j].x, acc1[r]);
                acc1[r] = fmaf(xv.y, a1[j].y, acc1[r]);
                acc1[r] = fmaf(xv.z, a1[j].z, acc1[r]);
                acc1[r] = fmaf(xv.w, a1[j].w, acc1[r]);
            }
        }
    }
    #pragma unroll
    for (int r = 0; r < RB; ++r) {
        sims[r][tid]       = acc0[r];
        sims[r][tid + 256] = acc1[r];
    }
    __syncthreads();

    // ---- top-5 per row: iterative wave argmax on the exact f32 sims,
    //      lowest-index tie-break (jax.lax.top_k semantics) ----
    for (int rr = 0; rr < RB/4; ++rr) {
        const int r = wave * (RB/4) + rr;
        float v[NP/64];
        #pragma unroll
        for (int j = 0; j < NP/64; ++j) v[j] = sims[r][lane + 64*j];
        float vsel[KSEL]; int isel[KSEL];
        #pragma unroll
        for (int it = 0; it < KSEL; ++it) {
            float bv = -1e30f; int bi = 0x7fffffff;
            #pragma unroll
            for (int j = 0; j < NP/64; ++j)
                if (v[j] > bv) { bv = v[j]; bi = lane + 64*j; }   // ascending j → low-index ties
            #pragma unroll
            for (int s = 32; s > 0; s >>= 1) {
                float ov = __shfl_xor(bv, s);
                int   oi = __shfl_xor(bi, s);
                if (ov > bv || (ov == bv && oi < bi)) { bv = ov; bi = oi; }
            }
            vsel[it] = bv; isel[it] = bi;
            #pragma unroll
            for (int j = 0; j < NP/64; ++j)        // eliminate winner
                if (bi == lane + 64*j) v[j] = -1e30f;
        }
        if (lane == 0) {
            // z = fl32(v / 0.2f) as the ref does, then softmax in f64 (value-level
            // differences ~1e-7 ≪ 8e-3 threshold)
            double z[KSEL];
            #pragma unroll
            for (int it = 0; it < KSEL; ++it) z[it] = (double)(vsel[it] / 0.2f);
            const double m = z[0];                 // first extracted is max
            double e[KSEL]; double sum = 0.0;
            #pragma unroll
            for (int it = 0; it < KSEL; ++it) { e[it] = exp(z[it] - m); sum += e[it]; }
            #pragma unroll
            for (int it = 0; it < KSEL; ++it) {
                top5v[r][it] = (float)(e[it] / sum);
                top5i[r][it] = isel[it];
            }
        }
    }
    __syncthreads();

    // ---- fused zero+scatter writeout: stream 16x512 region as float4 ----
    float* outb = out + r0 * NP;
    #pragma unroll
    for (int i = 0; i < (RB*NP/4)/NT; ++i) {   // 8 iters
        int fi = tid + i*NT;
        int r  = fi >> 7;                      // 128 float4 per row
        int c0 = (fi & 127) << 2;
        float4 vv = make_float4(0.f, 0.f, 0.f, 0.f);
        #pragma unroll
        for (int j = 0; j < KSEL; ++j) {
            int   idx = top5i[r][j];
            float val = top5v[r][j];
            if (c0     == idx) vv.x = val;
            if (c0 + 1 == idx) vv.y = val;
            if (c0 + 2 == idx) vv.z = val;
            if (c0 + 3 == idx) vv.w = val;
        }
        ((float4*)outb)[fi] = vv;
    }
}

extern "C" void kernel_launch(void* const* d_in, const int* in_sizes, int n_in,
                              void* d_out, int out_size, void* d_ws, size_t ws_size,
                              hipStream_t stream) {
    const float* x      = (const float*)d_in[0];
    const float* protos = (const float*)d_in[1];
    float* out = (float*)d_out;
    const int rows   = in_sizes[0] / DIM;     // 262144
    const int blocks = rows / RB;             // 16384
    hipLaunchKernelGGL(hub_kernel, dim3(blocks), dim3(NT), 0, stream,
                       x, protos, out);
}

// Round 5
// 1017.143 us; speedup vs baseline: 1.4713x; 1.4713x over previous
//
#include <hip/hip_runtime.h>
#include <math.h>

#define DIM   256
#define NP    512
#define RB    32
#define NT    256
#define PITCH 260            // xs row pitch in floats (pad -> bank spread)
#define BPITCH 40            // B_lds row pitch in halves (80 B, 16B-aligned rows)
#define CAND_CAP 16
#define KSEL  5

typedef float f32x4 __attribute__((ext_vector_type(4)));
typedef short short8 __attribute__((ext_vector_type(8)));

__device__ __forceinline__ unsigned short f32_to_bf16_rne(float f) {
    unsigned u = __float_as_uint(f);
    u += 0x7FFFu + ((u >> 16) & 1u);
    return (unsigned short)(u >> 16);
}
// pack two floats' bf16-truncations: (hi<<16)|lo
__device__ __forceinline__ unsigned pack_trunc2(float lo, float hi) {
    return (__float_as_uint(hi) & 0xFFFF0000u) | (__float_as_uint(lo) >> 16);
}

__global__ __launch_bounds__(NT, 2) void hub_kernel(
    const float* __restrict__ x,
    const float* __restrict__ protos,
    float* __restrict__ out)
{
    __shared__ float          xs[RB * PITCH];      // 33280 B (raw x, then xn)
    __shared__ unsigned short Blds[NP * BPITCH];   // 40960 B (per-kstep bf16 B tile)
    __shared__ float          nrm[RB];
    __shared__ unsigned int   ktop[RB][2][KSEL];   // per-half top-5 keys (descending)
    __shared__ unsigned int   u5[RB];              // exact union 5th-largest key
    __shared__ int            scnt[RB];
    __shared__ unsigned short cidx[RB][CAND_CAP];
    __shared__ float          cval[RB][CAND_CAP];
    __shared__ float          top5v[RB][KSEL];
    __shared__ int            top5i[RB][KSEL];

    const int tid  = threadIdx.x;
    const int wave = tid >> 6;
    const int lane = tid & 63;
    const size_t r0 = (size_t)blockIdx.x * RB;

    // ---- stage x tile (coalesced float4) into padded LDS ----
    {
        const float4* xg = (const float4*)(x + r0 * DIM);
        #pragma unroll
        for (int i = 0; i < 8; ++i) {
            int fi = tid + i * NT;
            int r = fi >> 6, c4 = fi & 63;
            *(float4*)(&xs[r * PITCH + c4 * 4]) = xg[fi];
        }
        if (tid < RB) scnt[tid] = 0;
    }
    __syncthreads();

    // ---- row norms: exact f64 sum -> f32 (frozen recipe from round 2) ----
    #pragma unroll
    for (int rr = 0; rr < 8; ++rr) {
        int r = wave * 8 + rr;
        double sq = 0.0;
        #pragma unroll
        for (int j = 0; j < 4; ++j) { double xv = (double)xs[r * PITCH + lane * 4 + j]; sq += xv * xv; }
        #pragma unroll
        for (int s = 32; s > 0; s >>= 1) sq += __shfl_xor(sq, s);
        if (lane == 0) nrm[r] = fmaxf(sqrtf((float)sq), 1e-12f);
    }
    __syncthreads();

    // ---- normalize in place: IEEE f32 divide (frozen) ----
    #pragma unroll
    for (int i = 0; i < 32; ++i) {
        int idx = tid + i * NT;
        int r = idx >> 8, d = idx & 255;
        xs[r * PITCH + d] = xs[r * PITCH + d] / nrm[r];
    }
    __syncthreads();

    // ---- per-wave geometry: rows (wave&1)*16, protos half (wave>>1)*256 ----
    const int half   = wave >> 1;
    const int rbase  = (wave & 1) * 16;
    const int mylane = lane & 15;
    const int kq     = lane >> 4;                  // k-octet within 32-chunk
    const int g      = lane >> 4;                  // C-layout row group

    // ---- A-fragments: xn rows -> bf16 (RNE), resident for all 8 k-steps ----
    short8 afr[8];
    {
        const int arow = rbase + mylane;
        #pragma unroll
        for (int ks = 0; ks < 8; ++ks) {
            const float* src = &xs[arow * PITCH + ks * 32 + kq * 8];
            float4 f0 = *(const float4*)(src);
            float4 f1 = *(const float4*)(src + 4);
            short8 a;
            a[0] = (short)f32_to_bf16_rne(f0.x); a[1] = (short)f32_to_bf16_rne(f0.y);
            a[2] = (short)f32_to_bf16_rne(f0.z); a[3] = (short)f32_to_bf16_rne(f0.w);
            a[4] = (short)f32_to_bf16_rne(f1.x); a[5] = (short)f32_to_bf16_rne(f1.y);
            a[6] = (short)f32_to_bf16_rne(f1.z); a[7] = (short)f32_to_bf16_rne(f1.w);
            afr[ks] = a;
        }
    }

    // ---- screening MFMA: per k-step stage all 512 protos' 32-dim bf16 slice ----
    f32x4 acc[16];
    #pragma unroll
    for (int t2 = 0; t2 < 16; ++t2) acc[t2] = (f32x4)(0.0f);

    for (int ks = 0; ks < 8; ++ks) {
        __syncthreads();                            // Blds reuse guard
        {
            const float4* s0 = (const float4*)(protos + (size_t)(2 * tid) * DIM + ks * 32);
            const float4* s1 = (const float4*)(protos + (size_t)(2 * tid + 1) * DIM + ks * 32);
            uint4* d0 = (uint4*)(&Blds[(2 * tid) * BPITCH]);
            uint4* d1 = (uint4*)(&Blds[(2 * tid + 1) * BPITCH]);
            #pragma unroll
            for (int q = 0; q < 4; ++q) {
                float4 fa = s0[2 * q], fb = s0[2 * q + 1];
                uint4 w;
                w.x = pack_trunc2(fa.x, fa.y); w.y = pack_trunc2(fa.z, fa.w);
                w.z = pack_trunc2(fb.x, fb.y); w.w = pack_trunc2(fb.z, fb.w);
                d0[q] = w;
            }
            #pragma unroll
            for (int q = 0; q < 4; ++q) {
                float4 fa = s1[2 * q], fb = s1[2 * q + 1];
                uint4 w;
                w.x = pack_trunc2(fa.x, fa.y); w.y = pack_trunc2(fa.z, fa.w);
                w.z = pack_trunc2(fb.x, fb.y); w.w = pack_trunc2(fb.z, fb.w);
                d1[q] = w;
            }
        }
        __syncthreads();
        #pragma unroll
        for (int t2 = 0; t2 < 16; ++t2) {
            int p = half * 256 + t2 * 16 + mylane;
            short8 b = *(const short8*)(&Blds[p * BPITCH + kq * 8]);
            acc[t2] = __builtin_amdgcn_mfma_f32_16x16x32_bf16(afr[ks], b, acc[t2], 0, 0, 0);
        }
    }

    // ---- per-half top-5 keys per row (descending), packed u32: monotone val | idx ----
    // C layout: col = lane&15 (proto), row = (lane>>4)*4 + reg  [m89-verified]
    #pragma unroll
    for (int m = 0; m < 4; ++m) {
        unsigned keys[16];
        #pragma unroll
        for (int t2 = 0; t2 < 16; ++t2) {
            unsigned u = __float_as_uint(fmaf(acc[t2][m], 0.25f, 1.5f));   // [1.25,1.75): fixed exp, monotone
            keys[t2] = (u & 0xFFFFFE00u) | (unsigned)(half * 256 + t2 * 16 + mylane);
        }
        #pragma unroll
        for (int it = 0; it < KSEL; ++it) {
            unsigned loc = 0;
            #pragma unroll
            for (int t2 = 0; t2 < 16; ++t2) loc = keys[t2] > loc ? keys[t2] : loc;
            #pragma unroll
            for (int s = 1; s < 16; s <<= 1) {
                unsigned o = (unsigned)__shfl_xor((int)loc, s);
                loc = o > loc ? o : loc;
            }
            if (mylane == 0) ktop[rbase + g * 4 + m][half][it] = loc;
            #pragma unroll
            for (int t2 = 0; t2 < 16; ++t2) keys[t2] = (keys[t2] == loc) ? 0u : keys[t2];
        }
    }
    __syncthreads();

    // ---- EXACT union 5th-largest key: 5-step merge of two descending 5-lists ----
    if (tid < RB) {
        unsigned L[KSEL], R[KSEL];
        #pragma unroll
        for (int j = 0; j < KSEL; ++j) { L[j] = ktop[tid][0][j]; R[j] = ktop[tid][1][j]; }
        int i = 0, j = 0; unsigned last = 0;
        #pragma unroll
        for (int s = 0; s < KSEL; ++s) {           // i+j = s <= 4, indices safe
            if (L[i] >= R[j]) last = L[i++]; else last = R[j++];
        }
        u5[tid] = last;
    }
    __syncthreads();

    // ---- candidate collection: key >= union5th - margin(1.95e-3) ----
    #pragma unroll
    for (int m = 0; m < 4; ++m) {
        int row = rbase + g * 4 + m;
        unsigned tk = (u5[row] & 0xFFFFFE00u) - 0x1000u;
        #pragma unroll
        for (int t2 = 0; t2 < 16; ++t2) {
            unsigned u = __float_as_uint(fmaf(acc[t2][m], 0.25f, 1.5f)) & 0xFFFFFE00u;
            if (u >= tk) {
                int slot = atomicAdd(&scnt[row], 1);
                if (slot < CAND_CAP) cidx[row][slot] = (unsigned short)(half * 256 + t2 * 16 + mylane);
            }
        }
    }
    __syncthreads();

    // ---- exact refine: frozen d-ascending fmaf chain (bit-identical to round 2) ----
    {
        int row = tid >> 3;
        int s0i = tid & 7, s1i = s0i + 8;
        int n = min(scnt[row], CAND_CAP);
        int p0 = (s0i < n) ? (int)cidx[row][s0i] : 0;
        int p1 = (s1i < n) ? (int)cidx[row][s1i] : 0;
        const float4* pr0 = (const float4*)(protos + (size_t)p0 * DIM);
        const float4* pr1 = (const float4*)(protos + (size_t)p1 * DIM);
        const float* xr = &xs[row * PITCH];
        float a0 = 0.f, a1 = 0.f;
        #pragma unroll 8
        for (int d4 = 0; d4 < 64; ++d4) {
            float4 xv = *(const float4*)(xr + d4 * 4);
            float4 q0 = pr0[d4];
            float4 q1 = pr1[d4];
            a0 = fmaf(xv.x, q0.x, a0); a0 = fmaf(xv.y, q0.y, a0);
            a0 = fmaf(xv.z, q0.z, a0); a0 = fmaf(xv.w, q0.w, a0);
            a1 = fmaf(xv.x, q1.x, a1); a1 = fmaf(xv.y, q1.y, a1);
            a1 = fmaf(xv.z, q1.z, a1); a1 = fmaf(xv.w, q1.w, a1);
        }
        if (s0i < n) cval[row][s0i] = a0;
        if (s1i < n) cval[row][s1i] = a1;
    }
    __syncthreads();

    // ---- exact top-5 among candidates (low-index ties) + f64 softmax (frozen) ----
    if (tid < RB) {
        int row = tid;
        int n = min(scnt[row], CAND_CAP);
        float vv[CAND_CAP]; int ii[CAND_CAP];
        #pragma unroll
        for (int j = 0; j < CAND_CAP; ++j) {
            vv[j] = (j < n) ? cval[row][j] : -1e30f;
            ii[j] = (j < n) ? (int)cidx[row][j] : 0x7fffffff;
        }
        float vsel[KSEL]; int isel[KSEL];
        #pragma unroll
        for (int it = 0; it < KSEL; ++it) {
            float bv = -1e30f; int bi = 0x7fffffff;
            #pragma unroll
            for (int j = 0; j < CAND_CAP; ++j)
                if (vv[j] > bv || (vv[j] == bv && ii[j] < bi)) { bv = vv[j]; bi = ii[j]; }
            vsel[it] = bv; isel[it] = bi;
            #pragma unroll
            for (int j = 0; j < CAND_CAP; ++j)
                if (ii[j] == bi) { vv[j] = -1e30f; ii[j] = 0x7fffffff; }
        }
        double z[KSEL];
        #pragma unroll
        for (int it = 0; it < KSEL; ++it) z[it] = (double)(vsel[it] / 0.2f);
        double mm = z[0]; double e[KSEL]; double sum = 0.0;
        #pragma unroll
        for (int it = 0; it < KSEL; ++it) { e[it] = exp(z[it] - mm); sum += e[it]; }
        #pragma unroll
        for (int it = 0; it < KSEL; ++it) {
            top5v[row][it] = (float)(e[it] / sum);
            top5i[row][it] = isel[it];
        }
    }
    __syncthreads();

    // ---- fused zero+scatter writeout: stream 32x512 as float4 ----
    float* outb = out + r0 * NP;
    #pragma unroll
    for (int i = 0; i < 16; ++i) {
        int fi = tid + i * NT;
        int r = fi >> 7, c0 = (fi & 127) << 2;
        float4 vvv = make_float4(0.f, 0.f, 0.f, 0.f);
        #pragma unroll
        for (int j = 0; j < KSEL; ++j) {
            int idx = top5i[r][j]; float val = top5v[r][j];
            if (c0     == idx) vvv.x = val;
            if (c0 + 1 == idx) vvv.y = val;
            if (c0 + 2 == idx) vvv.z = val;
            if (c0 + 3 == idx) vvv.w = val;
        }
        ((float4*)outb)[fi] = vvv;
    }
}

extern "C" void kernel_launch(void* const* d_in, const int* in_sizes, int n_in,
                              void* d_out, int out_size, void* d_ws, size_t ws_size,
                              hipStream_t stream) {
    const float* x      = (const float*)d_in[0];
    const float* protos = (const float*)d_in[1];
    float* out = (float*)d_out;
    const int rows   = in_sizes[0] / DIM;          // 262144
    const int blocks = rows / RB;                  // 8192
    hipLaunchKernelGGL(hub_kernel, dim3(blocks), dim3(NT), 0, stream,
                       x, protos, out);
}

// Round 6
// 645.571 us; speedup vs baseline: 2.3181x; 1.5756x over previous
//
#include <hip/hip_runtime.h>
#include <math.h>

#define DIM   256
#define NP    512
#define RB    32
#define NT    256
#define PITCH 260            // xs row pitch in floats (1040 B: 16B-aligned, bank spread)
#define CAND_CAP 16
#define KSEL  5

typedef float f32x4 __attribute__((ext_vector_type(4)));
typedef short short8 __attribute__((ext_vector_type(8)));

__device__ __forceinline__ unsigned short f32_to_bf16_rne(float f) {
    unsigned u = __float_as_uint(f);
    u += 0x7FFFu + ((u >> 16) & 1u);
    return (unsigned short)(u >> 16);
}

// One-shot: protos f32 [512][256] -> bf16 (truncation, bit-identical to round-5 B path)
// in MFMA-fragment order: pbf[(((pg*8+ks)*4+kq)*16+m)*8+dd] = trunc(protos[pg*16+m][ks*32+kq*8+dd])
// => wave fragment for (proto-group pg, k-step ks) is 1024 contiguous bytes, lane reads lane*16B.
__global__ __launch_bounds__(256) void protos_pack(const float* __restrict__ protos,
                                                   unsigned short* __restrict__ pbf) {
    int t  = blockIdx.x * 256 + threadIdx.x;       // 131072 threads
    int dd = t & 7;
    int m  = (t >> 3) & 15;
    int kq = (t >> 7) & 3;
    int ks = (t >> 9) & 7;
    int pg = t >> 12;
    float v = protos[(pg * 16 + m) * DIM + ks * 32 + kq * 8 + dd];
    pbf[t] = (unsigned short)(__float_as_uint(v) >> 16);
}

__global__ __launch_bounds__(NT, 4) void hub_kernel(
    const float* __restrict__ x,
    const float* __restrict__ protos,
    const unsigned short* __restrict__ pbf,        // fragment-ordered bf16 protos (d_ws)
    float* __restrict__ out)
{
    __shared__ float          xs[RB * PITCH];      // 33280 B (raw x, then xn)
    __shared__ float          nrm[RB];
    __shared__ unsigned int   ktop[RB][2][KSEL];   // per-half top-5 keys (descending)
    __shared__ unsigned int   u5[RB];              // exact union 5th-largest key
    __shared__ int            scnt[RB];
    __shared__ unsigned short cidx[RB][CAND_CAP];
    __shared__ float          cval[RB][CAND_CAP];
    __shared__ float          top5v[RB][KSEL];
    __shared__ int            top5i[RB][KSEL];

    const int tid  = threadIdx.x;
    const int wave = tid >> 6;
    const int lane = tid & 63;
    const size_t r0 = (size_t)blockIdx.x * RB;

    // ---- stage x tile (coalesced float4) into padded LDS ----
    {
        const float4* xg = (const float4*)(x + r0 * DIM);
        #pragma unroll
        for (int i = 0; i < 8; ++i) {
            int fi = tid + i * NT;
            int r = fi >> 6, c4 = fi & 63;
            *(float4*)(&xs[r * PITCH + c4 * 4]) = xg[fi];
        }
        if (tid < RB) scnt[tid] = 0;
    }
    __syncthreads();

    // ---- row norms: exact f64 sum -> f32 (frozen recipe) ----
    #pragma unroll
    for (int rr = 0; rr < 8; ++rr) {
        int r = wave * 8 + rr;
        double sq = 0.0;
        #pragma unroll
        for (int j = 0; j < 4; ++j) { double xv = (double)xs[r * PITCH + lane * 4 + j]; sq += xv * xv; }
        #pragma unroll
        for (int s = 32; s > 0; s >>= 1) sq += __shfl_xor(sq, s);
        if (lane == 0) nrm[r] = fmaxf(sqrtf((float)sq), 1e-12f);
    }
    __syncthreads();

    // ---- normalize in place: IEEE f32 divide (frozen) ----
    #pragma unroll
    for (int i = 0; i < 32; ++i) {
        int idx = tid + i * NT;
        int r = idx >> 8, d = idx & 255;
        xs[r * PITCH + d] = xs[r * PITCH + d] / nrm[r];
    }
    __syncthreads();

    // ---- per-wave geometry: rows (wave&1)*16, protos half (wave>>1)*256 ----
    const int half   = wave >> 1;
    const int rbase  = (wave & 1) * 16;
    const int mylane = lane & 15;
    const int kq     = lane >> 4;                  // k-octet within 32-chunk
    const int g      = lane >> 4;                  // C-layout row group

    // ---- screening MFMA: B fragments straight from global (L2-resident, coalesced);
    //      A fragment rebuilt per k-step (minimal live registers); NO LDS, NO syncs ----
    const short8* __restrict__ pbf8 = (const short8*)pbf;
    f32x4 acc[16];
    #pragma unroll
    for (int t2 = 0; t2 < 16; ++t2) acc[t2] = (f32x4)(0.0f);

    #pragma unroll
    for (int ks = 0; ks < 8; ++ks) {
        const float* src = &xs[(rbase + mylane) * PITCH + ks * 32 + kq * 8];
        float4 f0 = *(const float4*)(src);
        float4 f1 = *(const float4*)(src + 4);
        short8 a;
        a[0] = (short)f32_to_bf16_rne(f0.x); a[1] = (short)f32_to_bf16_rne(f0.y);
        a[2] = (short)f32_to_bf16_rne(f0.z); a[3] = (short)f32_to_bf16_rne(f0.w);
        a[4] = (short)f32_to_bf16_rne(f1.x); a[5] = (short)f32_to_bf16_rne(f1.y);
        a[6] = (short)f32_to_bf16_rne(f1.z); a[7] = (short)f32_to_bf16_rne(f1.w);
        #pragma unroll
        for (int t2 = 0; t2 < 16; ++t2) {
            short8 b = pbf8[((half * 16 + t2) * 8 + ks) * 64 + lane];
            acc[t2] = __builtin_amdgcn_mfma_f32_16x16x32_bf16(a, b, acc[t2], 0, 0, 0);
        }
    }

    // ---- per-half top-5 keys per row (descending), packed u32: monotone val | idx ----
    // C layout: col = lane&15 (proto), row = (lane>>4)*4 + reg  [m89-verified]
    #pragma unroll
    for (int m = 0; m < 4; ++m) {
        unsigned keys[16];
        #pragma unroll
        for (int t2 = 0; t2 < 16; ++t2) {
            unsigned u = __float_as_uint(fmaf(acc[t2][m], 0.25f, 1.5f));   // [1.25,1.75): fixed exp, monotone
            keys[t2] = (u & 0xFFFFFE00u) | (unsigned)(half * 256 + t2 * 16 + mylane);
        }
        #pragma unroll
        for (int it = 0; it < KSEL; ++it) {
            unsigned loc = 0;
            #pragma unroll
            for (int t2 = 0; t2 < 16; ++t2) loc = keys[t2] > loc ? keys[t2] : loc;
            #pragma unroll
            for (int s = 1; s < 16; s <<= 1) {
                unsigned o = (unsigned)__shfl_xor((int)loc, s);
                loc = o > loc ? o : loc;
            }
            if (mylane == 0) ktop[rbase + g * 4 + m][half][it] = loc;
            #pragma unroll
            for (int t2 = 0; t2 < 16; ++t2) keys[t2] = (keys[t2] == loc) ? 0u : keys[t2];
        }
    }
    __syncthreads();

    // ---- EXACT union 5th-largest key: 5-step merge of two descending 5-lists ----
    if (tid < RB) {
        unsigned L[KSEL], R[KSEL];
        #pragma unroll
        for (int j = 0; j < KSEL; ++j) { L[j] = ktop[tid][0][j]; R[j] = ktop[tid][1][j]; }
        int i = 0, j = 0; unsigned last = 0;
        #pragma unroll
        for (int s = 0; s < KSEL; ++s) {
            if (L[i] >= R[j]) last = L[i++]; else last = R[j++];
        }
        u5[tid] = last;
    }
    __syncthreads();

    // ---- candidate collection: key >= union5th - margin(1.95e-3) ----
    #pragma unroll
    for (int m = 0; m < 4; ++m) {
        int row = rbase + g * 4 + m;
        unsigned tk = (u5[row] & 0xFFFFFE00u) - 0x1000u;
        #pragma unroll
        for (int t2 = 0; t2 < 16; ++t2) {
            unsigned u = __float_as_uint(fmaf(acc[t2][m], 0.25f, 1.5f)) & 0xFFFFFE00u;
            if (u >= tk) {
                int slot = atomicAdd(&scnt[row], 1);
                if (slot < CAND_CAP) cidx[row][slot] = (unsigned short)(half * 256 + t2 * 16 + mylane);
            }
        }
    }
    __syncthreads();

    // ---- exact refine: frozen d-ascending fmaf chain; paired slots, skip empties ----
    {
        int row = tid >> 3;
        int s = tid & 7;
        int n = min(scnt[row], CAND_CAP);
        int i0 = 2 * s, i1 = 2 * s + 1;
        if (i0 < n) {
            int p0 = (int)cidx[row][i0];
            int p1 = (i1 < n) ? (int)cidx[row][i1] : p0;
            const float4* pr0 = (const float4*)(protos + (size_t)p0 * DIM);
            const float4* pr1 = (const float4*)(protos + (size_t)p1 * DIM);
            const float* xr = &xs[row * PITCH];
            float a0 = 0.f, a1 = 0.f;
            #pragma unroll 8
            for (int d4 = 0; d4 < 64; ++d4) {
                float4 xv = *(const float4*)(xr + d4 * 4);
                float4 q0 = pr0[d4];
                float4 q1 = pr1[d4];
                a0 = fmaf(xv.x, q0.x, a0); a0 = fmaf(xv.y, q0.y, a0);
                a0 = fmaf(xv.z, q0.z, a0); a0 = fmaf(xv.w, q0.w, a0);
                a1 = fmaf(xv.x, q1.x, a1); a1 = fmaf(xv.y, q1.y, a1);
                a1 = fmaf(xv.z, q1.z, a1); a1 = fmaf(xv.w, q1.w, a1);
            }
            cval[row][i0] = a0;
            if (i1 < n) cval[row][i1] = a1;
        }
    }
    __syncthreads();

    // ---- exact top-5 among candidates (low-index ties) + f64 softmax (frozen) ----
    if (tid < RB) {
        int row = tid;
        int n = min(scnt[row], CAND_CAP);
        float vv[CAND_CAP]; int ii[CAND_CAP];
        #pragma unroll
        for (int j = 0; j < CAND_CAP; ++j) {
            vv[j] = (j < n) ? cval[row][j] : -1e30f;
            ii[j] = (j < n) ? (int)cidx[row][j] : 0x7fffffff;
        }
        float vsel[KSEL]; int isel[KSEL];
        #pragma unroll
        for (int it = 0; it < KSEL; ++it) {
            float bv = -1e30f; int bi = 0x7fffffff;
            #pragma unroll
            for (int j = 0; j < CAND_CAP; ++j)
                if (vv[j] > bv || (vv[j] == bv && ii[j] < bi)) { bv = vv[j]; bi = ii[j]; }
            vsel[it] = bv; isel[it] = bi;
            #pragma unroll
            for (int j = 0; j < CAND_CAP; ++j)
                if (ii[j] == bi) { vv[j] = -1e30f; ii[j] = 0x7fffffff; }
        }
        double z[KSEL];
        #pragma unroll
        for (int it = 0; it < KSEL; ++it) z[it] = (double)(vsel[it] / 0.2f);
        double mm = z[0]; double e[KSEL]; double sum = 0.0;
        #pragma unroll
        for (int it = 0; it < KSEL; ++it) { e[it] = exp(z[it] - mm); sum += e[it]; }
        #pragma unroll
        for (int it = 0; it < KSEL; ++it) {
            top5v[row][it] = (float)(e[it] / sum);
            top5i[row][it] = isel[it];
        }
    }
    __syncthreads();

    // ---- fused zero+scatter writeout: stream 32x512 as float4 ----
    float* outb = out + r0 * NP;
    #pragma unroll
    for (int i = 0; i < 16; ++i) {
        int fi = tid + i * NT;
        int r = fi >> 7, c0 = (fi & 127) << 2;
        float4 vvv = make_float4(0.f, 0.f, 0.f, 0.f);
        #pragma unroll
        for (int j = 0; j < KSEL; ++j) {
            int idx = top5i[r][j]; float val = top5v[r][j];
            if (c0     == idx) vvv.x = val;
            if (c0 + 1 == idx) vvv.y = val;
            if (c0 + 2 == idx) vvv.z = val;
            if (c0 + 3 == idx) vvv.w = val;
        }
        ((float4*)outb)[fi] = vvv;
    }
}

extern "C" void kernel_launch(void* const* d_in, const int* in_sizes, int n_in,
                              void* d_out, int out_size, void* d_ws, size_t ws_size,
                              hipStream_t stream) {
    const float* x      = (const float*)d_in[0];
    const float* protos = (const float*)d_in[1];
    float* out = (float*)d_out;
    unsigned short* pbf = (unsigned short*)d_ws;   // 131072 bf16 = 256 KB scratch

    hipLaunchKernelGGL(protos_pack, dim3(512), dim3(256), 0, stream, protos, pbf);

    const int rows   = in_sizes[0] / DIM;          // 262144
    const int blocks = rows / RB;                  // 8192
    hipLaunchKernelGGL(hub_kernel, dim3(blocks), dim3(NT), 0, stream,
                       x, protos, pbf, out);
}

// Round 7
// 588.565 us; speedup vs baseline: 2.5427x; 1.0969x over previous
//
#include <hip/hip_runtime.h>
#include <math.h>

#define DIM   256
#define NP    512
#define RB    16
#define NT    256
#define PITCH 260            // xs row pitch in floats (1040 B: 16B-aligned, bank spread)
#define CAND_CAP 16
#define KSEL  5

typedef float f32x4 __attribute__((ext_vector_type(4)));
typedef short short8 __attribute__((ext_vector_type(8)));

__device__ __forceinline__ unsigned short f32_to_bf16_rne(float f) {
    unsigned u = __float_as_uint(f);
    u += 0x7FFFu + ((u >> 16) & 1u);
    return (unsigned short)(u >> 16);
}

// One-shot: protos f32 [512][256] -> bf16 (truncation, bit-identical to round-5/6 B path)
// in MFMA-fragment order: pbf[(((pg*8+ks)*4+kq)*16+m)*8+dd] = trunc(protos[pg*16+m][ks*32+kq*8+dd])
__global__ __launch_bounds__(256) void protos_pack(const float* __restrict__ protos,
                                                   unsigned short* __restrict__ pbf) {
    int t  = blockIdx.x * 256 + threadIdx.x;       // 131072 threads
    int dd = t & 7;
    int m  = (t >> 3) & 15;
    int kq = (t >> 7) & 3;
    int ks = (t >> 9) & 7;
    int pg = t >> 12;
    float v = protos[(pg * 16 + m) * DIM + ks * 32 + kq * 8 + dd];
    pbf[t] = (unsigned short)(__float_as_uint(v) >> 16);
}

__global__ __launch_bounds__(NT, 6) void hub_kernel(
    const float* __restrict__ x,
    const float* __restrict__ protos,
    const unsigned short* __restrict__ pbf,        // fragment-ordered bf16 protos (d_ws)
    float* __restrict__ out)
{
    __shared__ float          xs[RB * PITCH];      // 16640 B (raw x, then xn)
    __shared__ float          nrm[RB];
    __shared__ unsigned       selbuf[RB * 4 * KSEL]; // 1280 B: ktop, later overlaid by cval
    __shared__ unsigned       u5[RB];              // exact union 5th-largest key
    __shared__ int            scnt[RB];
    __shared__ unsigned short cidx[RB][CAND_CAP];
    __shared__ float          top5v[RB][KSEL];
    __shared__ int            top5i[RB][KSEL];

    unsigned (*ktop)[4][KSEL] = (unsigned(*)[4][KSEL])selbuf;   // live: selection..u5
    float    (*cval)[CAND_CAP] = (float(*)[CAND_CAP])selbuf;    // live: refine..top5 (disjoint)

    const int tid  = threadIdx.x;
    const int wave = tid >> 6;
    const int lane = tid & 63;
    const size_t r0 = (size_t)blockIdx.x * RB;

    // ---- stage x tile (coalesced float4) into padded LDS ----
    {
        const float4* xg = (const float4*)(x + r0 * DIM);
        #pragma unroll
        for (int i = 0; i < 4; ++i) {              // 1024 float4 / 256 thr
            int fi = tid + i * NT;
            int r = fi >> 6, c4 = fi & 63;
            *(float4*)(&xs[r * PITCH + c4 * 4]) = xg[fi];
        }
        if (tid < RB) scnt[tid] = 0;
    }
    __syncthreads();

    // ---- row norms: exact f64 sum -> f32 (frozen recipe) ----
    #pragma unroll
    for (int rr = 0; rr < 4; ++rr) {
        int r = wave * 4 + rr;
        double sq = 0.0;
        #pragma unroll
        for (int j = 0; j < 4; ++j) { double xv = (double)xs[r * PITCH + lane * 4 + j]; sq += xv * xv; }
        #pragma unroll
        for (int s = 32; s > 0; s >>= 1) sq += __shfl_xor(sq, s);
        if (lane == 0) nrm[r] = fmaxf(sqrtf((float)sq), 1e-12f);
    }
    __syncthreads();

    // ---- normalize in place: IEEE f32 divide (frozen) ----
    #pragma unroll
    for (int i = 0; i < 16; ++i) {
        int idx = tid + i * NT;
        int r = idx >> 8, d = idx & 255;
        xs[r * PITCH + d] = xs[r * PITCH + d] / nrm[r];
    }
    __syncthreads();

    // ---- per-wave geometry: all waves share the 16 rows; wave owns proto quarter ----
    const int qg     = wave;                       // proto quarter: qg*128 .. +128
    const int mylane = lane & 15;
    const int kq     = lane >> 4;                  // k-octet within 32-chunk
    const int g      = lane >> 4;                  // C-layout row group

    // ---- screening MFMA: 16 rows x 128 protos per wave; B from global (L2), no LDS ----
    const short8* __restrict__ pbf8 = (const short8*)pbf;
    f32x4 acc[8];
    #pragma unroll
    for (int t2 = 0; t2 < 8; ++t2) acc[t2] = (f32x4)(0.0f);

    #pragma unroll
    for (int ks = 0; ks < 8; ++ks) {
        const float* src = &xs[mylane * PITCH + ks * 32 + kq * 8];
        float4 f0 = *(const float4*)(src);
        float4 f1 = *(const float4*)(src + 4);
        short8 a;
        a[0] = (short)f32_to_bf16_rne(f0.x); a[1] = (short)f32_to_bf16_rne(f0.y);
        a[2] = (short)f32_to_bf16_rne(f0.z); a[3] = (short)f32_to_bf16_rne(f0.w);
        a[4] = (short)f32_to_bf16_rne(f1.x); a[5] = (short)f32_to_bf16_rne(f1.y);
        a[6] = (short)f32_to_bf16_rne(f1.z); a[7] = (short)f32_to_bf16_rne(f1.w);
        #pragma unroll
        for (int t2 = 0; t2 < 8; ++t2) {
            short8 b = pbf8[(size_t)qg * 4096 + t2 * 512 + ks * 64 + lane];
            acc[t2] = __builtin_amdgcn_mfma_f32_16x16x32_bf16(a, b, acc[t2], 0, 0, 0);
        }
    }

    // ---- per-quarter top-5 keys per row (descending), packed u32: monotone val | idx ----
    // C layout: col = lane&15 (proto), row = (lane>>4)*4 + reg  [m89-verified]
    #pragma unroll
    for (int m = 0; m < 4; ++m) {
        unsigned keys[8];
        #pragma unroll
        for (int t2 = 0; t2 < 8; ++t2) {
            unsigned u = __float_as_uint(fmaf(acc[t2][m], 0.25f, 1.5f));   // [1.25,1.75): fixed exp, monotone
            keys[t2] = (u & 0xFFFFFE00u) | (unsigned)(qg * 128 + t2 * 16 + mylane);
        }
        #pragma unroll
        for (int it = 0; it < KSEL; ++it) {
            unsigned loc = 0;
            #pragma unroll
            for (int t2 = 0; t2 < 8; ++t2) loc = keys[t2] > loc ? keys[t2] : loc;
            #pragma unroll
            for (int s = 1; s < 16; s <<= 1) {                 // 16-lane group reduce
                unsigned o = (unsigned)__shfl_xor((int)loc, s);
                loc = o > loc ? o : loc;
            }
            if (mylane == 0) ktop[g * 4 + m][qg][it] = loc;
            #pragma unroll
            for (int t2 = 0; t2 < 8; ++t2) keys[t2] = (keys[t2] == loc) ? 0u : keys[t2];
        }
    }
    __syncthreads();

    // ---- EXACT union 5th-largest key: merge 4 descending 5-lists pairwise ----
    if (tid < RB) {
        unsigned A[KSEL], B[KSEL], M1[KSEL], M2[KSEL];
        #pragma unroll
        for (int j = 0; j < KSEL; ++j) { A[j] = ktop[tid][0][j]; B[j] = ktop[tid][1][j]; }
        { int i = 0, j = 0;
          #pragma unroll
          for (int s = 0; s < KSEL; ++s) { M1[s] = (A[i] >= B[j]) ? A[i++] : B[j++]; } }
        #pragma unroll
        for (int j = 0; j < KSEL; ++j) { A[j] = ktop[tid][2][j]; B[j] = ktop[tid][3][j]; }
        { int i = 0, j = 0;
          #pragma unroll
          for (int s = 0; s < KSEL; ++s) { M2[s] = (A[i] >= B[j]) ? A[i++] : B[j++]; } }
        { int i = 0, j = 0; unsigned last = 0;
          #pragma unroll
          for (int s = 0; s < KSEL; ++s) { last = (M1[i] >= M2[j]) ? M1[i++] : M2[j++]; }
          u5[tid] = last; }
    }
    __syncthreads();

    // ---- candidate collection: key >= union5th - margin(1.95e-3) ----
    #pragma unroll
    for (int m = 0; m < 4; ++m) {
        int row = g * 4 + m;
        unsigned tk = (u5[row] & 0xFFFFFE00u) - 0x1000u;
        #pragma unroll
        for (int t2 = 0; t2 < 8; ++t2) {
            unsigned u = __float_as_uint(fmaf(acc[t2][m], 0.25f, 1.5f)) & 0xFFFFFE00u;
            if (u >= tk) {
                int slot = atomicAdd(&scnt[row], 1);
                if (slot < CAND_CAP) cidx[row][slot] = (unsigned short)(qg * 128 + t2 * 16 + mylane);
            }
        }
    }
    __syncthreads();

    // ---- exact refine: frozen d-ascending fmaf chain; 16 threads/row, 1 proto each ----
    {
        int row = tid >> 4;
        int slot = tid & 15;
        int n = min(scnt[row], CAND_CAP);
        if (slot < n) {
            int p = (int)cidx[row][slot];
            const float4* pr = (const float4*)(protos + (size_t)p * DIM);
            const float* xr = &xs[row * PITCH];
            float a0 = 0.f;
            #pragma unroll 8
            for (int d4 = 0; d4 < 64; ++d4) {
                float4 xv = *(const float4*)(xr + d4 * 4);
                float4 q = pr[d4];
                a0 = fmaf(xv.x, q.x, a0); a0 = fmaf(xv.y, q.y, a0);
                a0 = fmaf(xv.z, q.z, a0); a0 = fmaf(xv.w, q.w, a0);
            }
            cval[row][slot] = a0;
        }
    }
    __syncthreads();

    // ---- exact top-5 among candidates (low-index ties) + f64 softmax (frozen) ----
    if (tid < RB) {
        int row = tid;
        int n = min(scnt[row], CAND_CAP);
        float vv[CAND_CAP]; int ii[CAND_CAP];
        #pragma unroll
        for (int j = 0; j < CAND_CAP; ++j) {
            vv[j] = (j < n) ? cval[row][j] : -1e30f;
            ii[j] = (j < n) ? (int)cidx[row][j] : 0x7fffffff;
        }
        float vsel[KSEL]; int isel[KSEL];
        #pragma unroll
        for (int it = 0; it < KSEL; ++it) {
            float bv = -1e30f; int bi = 0x7fffffff;
            #pragma unroll
            for (int j = 0; j < CAND_CAP; ++j)
                if (vv[j] > bv || (vv[j] == bv && ii[j] < bi)) { bv = vv[j]; bi = ii[j]; }
            vsel[it] = bv; isel[it] = bi;
            #pragma unroll
            for (int j = 0; j < CAND_CAP; ++j)
                if (ii[j] == bi) { vv[j] = -1e30f; ii[j] = 0x7fffffff; }
        }
        double z[KSEL];
        #pragma unroll
        for (int it = 0; it < KSEL; ++it) z[it] = (double)(vsel[it] / 0.2f);
        double mm = z[0]; double e[KSEL]; double sum = 0.0;
        #pragma unroll
        for (int it = 0; it < KSEL; ++it) { e[it] = exp(z[it] - mm); sum += e[it]; }
        #pragma unroll
        for (int it = 0; it < KSEL; ++it) {
            top5v[row][it] = (float)(e[it] / sum);
            top5i[row][it] = isel[it];
        }
    }
    __syncthreads();

    // ---- fused zero+scatter writeout: stream 16x512 as float4 ----
    float* outb = out + r0 * NP;
    #pragma unroll
    for (int i = 0; i < 8; ++i) {
        int fi = tid + i * NT;
        int r = fi >> 7, c0 = (fi & 127) << 2;
        float4 vvv = make_float4(0.f, 0.f, 0.f, 0.f);
        #pragma unroll
        for (int j = 0; j < KSEL; ++j) {
            int idx = top5i[r][j]; float val = top5v[r][j];
            if (c0     == idx) vvv.x = val;
            if (c0 + 1 == idx) vvv.y = val;
            if (c0 + 2 == idx) vvv.z = val;
            if (c0 + 3 == idx) vvv.w = val;
        }
        ((float4*)outb)[fi] = vvv;
    }
}

extern "C" void kernel_launch(void* const* d_in, const int* in_sizes, int n_in,
                              void* d_out, int out_size, void* d_ws, size_t ws_size,
                              hipStream_t stream) {
    const float* x      = (const float*)d_in[0];
    const float* protos = (const float*)d_in[1];
    float* out = (float*)d_out;
    unsigned short* pbf = (unsigned short*)d_ws;   // 131072 bf16 = 256 KB scratch

    hipLaunchKernelGGL(protos_pack, dim3(512), dim3(256), 0, stream, protos, pbf);

    const int rows   = in_sizes[0] / DIM;          // 262144
    const int blocks = rows / RB;                  // 16384
    hipLaunchKernelGGL(hub_kernel, dim3(blocks), dim3(NT), 0, stream,
                       x, protos, pbf, out);
}

// Round 8
// 580.644 us; speedup vs baseline: 2.5773x; 1.0136x over previous
//
#include <hip/hip_runtime.h>
#include <math.h>

#define DIM   256
#define NP    512
#define RB    16
#define NT    256
#define PITCH 260            // xs row pitch in floats (1040 B: 16B-aligned, bank spread)
#define CAND_CAP 16
#define KSEL  5

typedef float f32x4 __attribute__((ext_vector_type(4)));
typedef short short8 __attribute__((ext_vector_type(8)));

__device__ __forceinline__ unsigned short f32_to_bf16_rne(float f) {
    unsigned u = __float_as_uint(f);
    u += 0x7FFFu + ((u >> 16) & 1u);
    return (unsigned short)(u >> 16);
}

// One-shot: protos f32 [512][256] -> bf16 (truncation, bit-identical to round-5/6/7 B path)
// in MFMA-fragment order: pbf[(((pg*8+ks)*4+kq)*16+m)*8+dd] = trunc(protos[pg*16+m][ks*32+kq*8+dd])
__global__ __launch_bounds__(256) void protos_pack(const float* __restrict__ protos,
                                                   unsigned short* __restrict__ pbf) {
    int t  = blockIdx.x * 256 + threadIdx.x;       // 131072 threads
    int dd = t & 7;
    int m  = (t >> 3) & 15;
    int kq = (t >> 7) & 3;
    int ks = (t >> 9) & 7;
    int pg = t >> 12;
    float v = protos[(pg * 16 + m) * DIM + ks * 32 + kq * 8 + dd];
    pbf[t] = (unsigned short)(__float_as_uint(v) >> 16);
}

__global__ __launch_bounds__(NT, 6) void hub_kernel(
    const float* __restrict__ x,
    const float* __restrict__ protos,
    const unsigned short* __restrict__ pbf,        // fragment-ordered bf16 protos (d_ws)
    float* __restrict__ out)
{
    __shared__ float          xs[RB * PITCH];      // 16640 B (raw x, then xn)
    __shared__ float          nrm[RB];
    __shared__ unsigned       selbuf[RB * 4 * KSEL]; // 1280 B: ktop, later overlaid by cval
    __shared__ unsigned       u5[RB];              // exact union 5th-largest key
    __shared__ int            scnt[RB];
    __shared__ unsigned short cidx[RB][CAND_CAP];
    __shared__ float          top5v[RB][KSEL];
    __shared__ int            top5i[RB][KSEL];

    unsigned (*ktop)[4][KSEL] = (unsigned(*)[4][KSEL])selbuf;   // live: selection..u5
    float    (*cval)[CAND_CAP] = (float(*)[CAND_CAP])selbuf;    // live: refine..top5 (disjoint)

    const int tid  = threadIdx.x;
    const int wave = tid >> 6;
    const int lane = tid & 63;
    const size_t r0 = (size_t)blockIdx.x * RB;

    // ---- stage x tile (coalesced float4) into padded LDS ----
    {
        const float4* xg = (const float4*)(x + r0 * DIM);
        #pragma unroll
        for (int i = 0; i < 4; ++i) {              // 1024 float4 / 256 thr
            int fi = tid + i * NT;
            int r = fi >> 6, c4 = fi & 63;
            *(float4*)(&xs[r * PITCH + c4 * 4]) = xg[fi];
        }
        if (tid < RB) scnt[tid] = 0;
    }
    __syncthreads();

    // ---- row norms: exact f64 sum -> f32 (frozen recipe) ----
    #pragma unroll
    for (int rr = 0; rr < 4; ++rr) {
        int r = wave * 4 + rr;
        double sq = 0.0;
        #pragma unroll
        for (int j = 0; j < 4; ++j) { double xv = (double)xs[r * PITCH + lane * 4 + j]; sq += xv * xv; }
        #pragma unroll
        for (int s = 32; s > 0; s >>= 1) sq += __shfl_xor(sq, s);
        if (lane == 0) nrm[r] = fmaxf(sqrtf((float)sq), 1e-12f);
    }
    __syncthreads();

    // ---- normalize in place: IEEE f32 divide (frozen) ----
    #pragma unroll
    for (int i = 0; i < 16; ++i) {
        int idx = tid + i * NT;
        int r = idx >> 8, d = idx & 255;
        xs[r * PITCH + d] = xs[r * PITCH + d] / nrm[r];
    }
    __syncthreads();

    // ---- per-wave geometry: all waves share the 16 rows; wave owns proto quarter ----
    const int qg     = wave;                       // proto quarter: qg*128 .. +128
    const int mylane = lane & 15;
    const int kq     = lane >> 4;                  // k-octet within 32-chunk
    const int g      = lane >> 4;                  // C-layout row group

    // ---- screening MFMA: 16 rows x 128 protos per wave; B from global (L2), no LDS ----
    const short8* __restrict__ pbf8 = (const short8*)pbf;
    f32x4 acc[8];
    #pragma unroll
    for (int t2 = 0; t2 < 8; ++t2) acc[t2] = (f32x4)(0.0f);

    #pragma unroll
    for (int ks = 0; ks < 8; ++ks) {
        const float* src = &xs[mylane * PITCH + ks * 32 + kq * 8];
        float4 f0 = *(const float4*)(src);
        float4 f1 = *(const float4*)(src + 4);
        short8 a;
        a[0] = (short)f32_to_bf16_rne(f0.x); a[1] = (short)f32_to_bf16_rne(f0.y);
        a[2] = (short)f32_to_bf16_rne(f0.z); a[3] = (short)f32_to_bf16_rne(f0.w);
        a[4] = (short)f32_to_bf16_rne(f1.x); a[5] = (short)f32_to_bf16_rne(f1.y);
        a[6] = (short)f32_to_bf16_rne(f1.z); a[7] = (short)f32_to_bf16_rne(f1.w);
        #pragma unroll
        for (int t2 = 0; t2 < 8; ++t2) {
            short8 b = pbf8[(size_t)qg * 4096 + t2 * 512 + ks * 64 + lane];
            acc[t2] = __builtin_amdgcn_mfma_f32_16x16x32_bf16(a, b, acc[t2], 0, 0, 0);
        }
    }

    // ---- per-quarter top-5 keys per row (descending), packed u32: monotone val | idx ----
    // C layout: col = lane&15 (proto), row = (lane>>4)*4 + reg  [m89-verified]
    #pragma unroll
    for (int m = 0; m < 4; ++m) {
        unsigned keys[8];
        #pragma unroll
        for (int t2 = 0; t2 < 8; ++t2) {
            unsigned u = __float_as_uint(fmaf(acc[t2][m], 0.25f, 1.5f));   // [1.25,1.75): fixed exp, monotone
            keys[t2] = (u & 0xFFFFFE00u) | (unsigned)(qg * 128 + t2 * 16 + mylane);
        }
        #pragma unroll
        for (int it = 0; it < KSEL; ++it) {
            unsigned loc = 0;
            #pragma unroll
            for (int t2 = 0; t2 < 8; ++t2) loc = keys[t2] > loc ? keys[t2] : loc;
            #pragma unroll
            for (int s = 1; s < 16; s <<= 1) {                 // 16-lane group reduce
                unsigned o = (unsigned)__shfl_xor((int)loc, s);
                loc = o > loc ? o : loc;
            }
            if (mylane == 0) ktop[g * 4 + m][qg][it] = loc;
            #pragma unroll
            for (int t2 = 0; t2 < 8; ++t2) keys[t2] = (keys[t2] == loc) ? 0u : keys[t2];
        }
    }
    __syncthreads();

    // ---- EXACT union 5th-largest key: merge 4 descending 5-lists pairwise ----
    if (tid < RB) {
        unsigned A[KSEL], B[KSEL], M1[KSEL], M2[KSEL];
        #pragma unroll
        for (int j = 0; j < KSEL; ++j) { A[j] = ktop[tid][0][j]; B[j] = ktop[tid][1][j]; }
        { int i = 0, j = 0;
          #pragma unroll
          for (int s = 0; s < KSEL; ++s) { M1[s] = (A[i] >= B[j]) ? A[i++] : B[j++]; } }
        #pragma unroll
        for (int j = 0; j < KSEL; ++j) { A[j] = ktop[tid][2][j]; B[j] = ktop[tid][3][j]; }
        { int i = 0, j = 0;
          #pragma unroll
          for (int s = 0; s < KSEL; ++s) { M2[s] = (A[i] >= B[j]) ? A[i++] : B[j++]; } }
        { int i = 0, j = 0; unsigned last = 0;
          #pragma unroll
          for (int s = 0; s < KSEL; ++s) { last = (M1[i] >= M2[j]) ? M1[i++] : M2[j++]; }
          u5[tid] = last; }
    }
    __syncthreads();

    // ---- candidate collection: key >= union5th - margin(1.95e-3) ----
    #pragma unroll
    for (int m = 0; m < 4; ++m) {
        int row = g * 4 + m;
        unsigned tk = (u5[row] & 0xFFFFFE00u) - 0x1000u;
        #pragma unroll
        for (int t2 = 0; t2 < 8; ++t2) {
            unsigned u = __float_as_uint(fmaf(acc[t2][m], 0.25f, 1.5f)) & 0xFFFFFE00u;
            if (u >= tk) {
                int slot = atomicAdd(&scnt[row], 1);
                if (slot < CAND_CAP) cidx[row][slot] = (unsigned short)(qg * 128 + t2 * 16 + mylane);
            }
        }
    }
    __syncthreads();

    // ---- exact refine: frozen d-ascending fmaf chain; 16 threads/row, 1 proto each ----
    {
        int row = tid >> 4;
        int slot = tid & 15;
        int n = min(scnt[row], CAND_CAP);
        if (slot < n) {
            int p = (int)cidx[row][slot];
            const float4* pr = (const float4*)(protos + (size_t)p * DIM);
            const float* xr = &xs[row * PITCH];
            float a0 = 0.f;
            #pragma unroll 8
            for (int d4 = 0; d4 < 64; ++d4) {
                float4 xv = *(const float4*)(xr + d4 * 4);
                float4 q = pr[d4];
                a0 = fmaf(xv.x, q.x, a0); a0 = fmaf(xv.y, q.y, a0);
                a0 = fmaf(xv.z, q.z, a0); a0 = fmaf(xv.w, q.w, a0);
            }
            cval[row][slot] = a0;
        }
    }
    __syncthreads();

    // ---- exact top-5 among candidates (low-index ties) + f32 softmax ----
    if (tid < RB) {
        int row = tid;
        int n = min(scnt[row], CAND_CAP);
        float vv[CAND_CAP]; int ii[CAND_CAP];
        #pragma unroll
        for (int j = 0; j < CAND_CAP; ++j) {
            vv[j] = (j < n) ? cval[row][j] : -1e30f;
            ii[j] = (j < n) ? (int)cidx[row][j] : 0x7fffffff;
        }
        float vsel[KSEL]; int isel[KSEL];
        #pragma unroll
        for (int it = 0; it < KSEL; ++it) {
            float bv = -1e30f; int bi = 0x7fffffff;
            #pragma unroll
            for (int j = 0; j < CAND_CAP; ++j)
                if (vv[j] > bv || (vv[j] == bv && ii[j] < bi)) { bv = vv[j]; bi = ii[j]; }
            vsel[it] = bv; isel[it] = bi;
            #pragma unroll
            for (int j = 0; j < CAND_CAP; ++j)
                if (ii[j] == bi) { vv[j] = -1e30f; ii[j] = 0x7fffffff; }
        }
        // softmax values in f32 (selection unaffected; value error ~1e-7 << 8e-3 threshold)
        float z[KSEL];
        #pragma unroll
        for (int it = 0; it < KSEL; ++it) z[it] = vsel[it] / 0.2f;
        float mm = z[0]; float e[KSEL]; float sum = 0.0f;
        #pragma unroll
        for (int it = 0; it < KSEL; ++it) { e[it] = expf(z[it] - mm); sum += e[it]; }
        #pragma unroll
        for (int it = 0; it < KSEL; ++it) {
            top5v[row][it] = e[it] / sum;
            top5i[row][it] = isel[it];
        }
    }
    __syncthreads();

    // ---- writeout: stream zeros (no selects), then scatter 5 dwords/row ----
    float* outb = out + r0 * NP;
    {
        const float4 zz = make_float4(0.f, 0.f, 0.f, 0.f);
        #pragma unroll
        for (int i = 0; i < 8; ++i)
            ((float4*)outb)[tid + i * NT] = zz;
    }
    __syncthreads();                               // drains vmcnt -> zeros ordered before scatter
    if (tid < RB * KSEL) {                         // 80 threads
        int row = tid / KSEL, j = tid - row * KSEL;
        outb[row * NP + top5i[row][j]] = top5v[row][j];
    }
}

extern "C" void kernel_launch(void* const* d_in, const int* in_sizes, int n_in,
                              void* d_out, int out_size, void* d_ws, size_t ws_size,
                              hipStream_t stream) {
    const float* x      = (const float*)d_in[0];
    const float* protos = (const float*)d_in[1];
    float* out = (float*)d_out;
    unsigned short* pbf = (unsigned short*)d_ws;   // 131072 bf16 = 256 KB scratch

    hipLaunchKernelGGL(protos_pack, dim3(512), dim3(256), 0, stream, protos, pbf);

    const int rows   = in_sizes[0] / DIM;          // 262144
    const int blocks = rows / RB;                  // 16384
    hipLaunchKernelGGL(hub_kernel, dim3(blocks), dim3(NT), 0, stream,
                       x, protos, pbf, out);
}